// Round 4
// baseline (707.515 us; speedup 1.0000x reference)
//
#include <hip/hip_runtime.h>
#include <math.h>

// ---------------------------------------------------------------------------
// JKNet: 2-layer GCN (sym-norm A+I) + sum-JK + linear + log_softmax.
// Round 4: latency-optimized gather — (src,weight) int2 edge pairs built in
// permute (kills dis-load from the chain), 2 nodes/wave with batched unroll-4
// loads (8 row-gathers in flight). bf16 MFMA GEMMs unchanged.
// ---------------------------------------------------------------------------

#define NPAD (1 << 17)   // padded node-array stride (N=100000)
#define CHUNK 1024       // scan chunk (elements per block)

typedef __attribute__((ext_vector_type(8))) short short8;
typedef __attribute__((ext_vector_type(4))) float f32x4;

__device__ inline unsigned short f2bf(float f) {
    unsigned u = __builtin_bit_cast(unsigned, f);
    return (unsigned short)((u + 0x7fffu + ((u >> 16) & 1u)) >> 16);
}
__device__ inline float bflo(unsigned u) { return __builtin_bit_cast(float, u << 16); }
__device__ inline float bfhi(unsigned u) { return __builtin_bit_cast(float, u & 0xffff0000u); }

// ---- CSR build ------------------------------------------------------------

__global__ void hist_kernel(const int* __restrict__ dst, int* __restrict__ cnt, int E) {
    int e = blockIdx.x * 256 + threadIdx.x;
    if (e < E) atomicAdd(&cnt[dst[e]], 1);
}

__global__ void scan_partial(const int* __restrict__ cnt, int* __restrict__ partial, int n) {
    __shared__ int sdata[4];
    int b = blockIdx.x, t = threadIdx.x;
    int base = b * CHUNK;
    int sum = 0;
    for (int i = t; i < CHUNK; i += 256) {
        int idx = base + i;
        if (idx < n) sum += cnt[idx];
    }
#pragma unroll
    for (int off = 32; off > 0; off >>= 1) sum += __shfl_down(sum, off, 64);
    if ((t & 63) == 0) sdata[t >> 6] = sum;
    __syncthreads();
    if (t == 0) partial[b] = sdata[0] + sdata[1] + sdata[2] + sdata[3];
}

__global__ void scan_small(int* partial, int nblk) {
    if (threadIdx.x == 0 && blockIdx.x == 0) {
        int acc = 0;
        for (int i = 0; i < nblk; i++) { int v = partial[i]; partial[i] = acc; acc += v; }
    }
}

__global__ void scan_final(const int* __restrict__ cnt, const int* __restrict__ partial,
                           int* __restrict__ offs, int* __restrict__ cursor,
                           float* __restrict__ dis, int n) {
    __shared__ int wsum[4];
    int b = blockIdx.x, t = threadIdx.x;
    int lane = t & 63, w = t >> 6;
    int base = b * CHUNK + t * 4;
    int v[4];
#pragma unroll
    for (int j = 0; j < 4; j++) v[j] = (base + j < n) ? cnt[base + j] : 0;
    int s4 = v[0] + v[1] + v[2] + v[3];
    int inc = s4;
#pragma unroll
    for (int off = 1; off < 64; off <<= 1) {
        int x = __shfl_up(inc, off, 64);
        if (lane >= off) inc += x;
    }
    if (lane == 63) wsum[w] = inc;
    __syncthreads();
    int woff = 0;
    for (int i = 0; i < 4; i++) if (i < w) woff += wsum[i];
    int pos = partial[b] + woff + (inc - s4);
#pragma unroll
    for (int j = 0; j < 4; j++) {
        int idx = base + j;
        if (idx < n) {
            offs[idx] = pos;
            cursor[idx] = pos;
            dis[idx] = rsqrtf((float)(v[j] + 1));  // deg = incoming + self-loop
            pos += v[j];
        }
    }
}

// Bucketed permute: edges with dst in [lo,hi) only — cursor atomics and eadj
// scatter writes stay inside an L2-resident window. Stores (src, dis[s]*dis[d]).
__global__ void permute_bucket(const int* __restrict__ src, const int* __restrict__ dst,
                               const float* __restrict__ dis,
                               int* __restrict__ cursor, int2* __restrict__ eadj,
                               int E, int lo, int hi) {
    int e = blockIdx.x * 256 + threadIdx.x;
    if (e < E) {
        int d = dst[e];
        if (d >= lo && d < hi) {
            int s = src[e];
            int pos = atomicAdd(&cursor[d], 1);
            float wt = dis[s] * dis[d];
            eadj[pos] = make_int2(s, __float_as_int(wt));
        }
    }
}

// ---- W cast+transpose: Wt[n][k] = bf16(W[k][n]) ---------------------------
__global__ void wcast(const float* __restrict__ W, unsigned short* __restrict__ Wt, int K) {
    int i = blockIdx.x * 256 + threadIdx.x;
    if (i < K * 128) {
        int k = i >> 7, nn = i & 127;
        Wt[nn * K + k] = f2bf(W[i]);
    }
}

// ---- MFMA GEMM: Hb[n,128](bf16) = A[n,K] @ W[K,128] -----------------------
template<bool ABF16>
__global__ __launch_bounds__(256) void gemm_mfma(const void* __restrict__ Ap,
                                                 const unsigned short* __restrict__ Wt,
                                                 unsigned short* __restrict__ Hb,
                                                 int n, int K) {
    __shared__ unsigned short bs[128 * 136];
    const int tid = threadIdx.x;
    const int wave = tid >> 6, lane = tid & 63;
    const int quad = lane >> 4, mrow = lane & 15;
    const int arow_g = blockIdx.x * 64 + wave * 16 + mrow;
    const int arow = arow_g < n ? arow_g : n - 1;

    f32x4 acc[8];
#pragma unroll
    for (int t = 0; t < 8; t++) acc[t] = (f32x4){0.f, 0.f, 0.f, 0.f};

    const float* Af = (const float*)Ap;
    const unsigned short* Ab = (const unsigned short*)Ap;

    for (int kc = 0; kc < K; kc += 128) {
        __syncthreads();
        for (int i = tid; i < 2048; i += 256) {
            int row = i >> 4, c8 = i & 15;
            *(short8*)&bs[row * 136 + c8 * 8] = *(const short8*)&Wt[row * K + kc + c8 * 8];
        }
        __syncthreads();
#pragma unroll
        for (int kt = 0; kt < 128; kt += 32) {
            union { short8 v; unsigned short u[8]; } A;
            if (ABF16) {
                A.v = *(const short8*)&Ab[(size_t)arow * K + kc + kt + quad * 8];
            } else {
                const float* ap = &Af[(size_t)arow * K + kc + kt + quad * 8];
                float4 p0 = *(const float4*)ap;
                float4 p1 = *(const float4*)(ap + 4);
                A.u[0] = f2bf(p0.x); A.u[1] = f2bf(p0.y);
                A.u[2] = f2bf(p0.z); A.u[3] = f2bf(p0.w);
                A.u[4] = f2bf(p1.x); A.u[5] = f2bf(p1.y);
                A.u[6] = f2bf(p1.z); A.u[7] = f2bf(p1.w);
            }
#pragma unroll
            for (int nt = 0; nt < 8; nt++) {
                short8 B = *(const short8*)&bs[(nt * 16 + mrow) * 136 + kt + quad * 8];
                acc[nt] = __builtin_amdgcn_mfma_f32_16x16x32_bf16(A.v, B, acc[nt], 0, 0, 0);
            }
        }
    }
    const int drow0 = blockIdx.x * 64 + wave * 16 + quad * 4;
#pragma unroll
    for (int r = 0; r < 4; r++) {
        int dr = drow0 + r;
        if (dr < n) {
#pragma unroll
            for (int nt = 0; nt < 8; nt++)
                Hb[(size_t)dr * 128 + nt * 16 + mrow] = f2bf(acc[nt][r]);
        }
    }
}

// ---- CSR gather (+optional fused JK head) ---------------------------------
// 2 nodes per wave, unroll-4, loads explicitly batched: 8 row-gathers + 8
// pair-loads in flight per iteration; weights pre-folded (no dis in chain).
template<bool FUSE>
__global__ __launch_bounds__(256) void gather_k(const unsigned short* __restrict__ Hb,
                                                const int2* __restrict__ eadj,
                                                const int* __restrict__ offs,
                                                const int* __restrict__ cnt,
                                                const float* __restrict__ dis,
                                                const float* __restrict__ bias,
                                                unsigned short* __restrict__ outb,
                                                const unsigned short* __restrict__ x1b,
                                                const float* __restrict__ lw,
                                                const float* __restrict__ lb,
                                                float* __restrict__ out, int n) {
    __shared__ float s[8][128];
    const int w = threadIdx.x >> 6, lane = threadIdx.x & 63;
    const int node0 = blockIdx.x * 8 + w * 2;
    const int nd0 = node0 < n ? node0 : n - 1;
    const int nd1 = node0 + 1 < n ? node0 + 1 : n - 1;
    const unsigned* Hu = (const unsigned*)Hb;

    int st0 = offs[nd0], c0 = cnt[nd0];
    int st1 = offs[nd1], c1 = cnt[nd1];
    float a00 = 0.f, a01 = 0.f, a10 = 0.f, a11 = 0.f;

    int cmax = c0 > c1 ? c0 : c1;
    for (int j = 0; j < cmax; j += 4) {
        int2 e0[4], e1[4];
#pragma unroll
        for (int k = 0; k < 4; k++) {
            e0[k] = (j + k < c0) ? eadj[st0 + j + k] : make_int2(0, 0);
            e1[k] = (j + k < c1) ? eadj[st1 + j + k] : make_int2(0, 0);
        }
        unsigned u0[4], u1[4];
#pragma unroll
        for (int k = 0; k < 4; k++) u0[k] = Hu[(size_t)e0[k].x * 64 + lane];
#pragma unroll
        for (int k = 0; k < 4; k++) u1[k] = Hu[(size_t)e1[k].x * 64 + lane];
#pragma unroll
        for (int k = 0; k < 4; k++) {
            float w0 = __int_as_float(e0[k].y);
            float w1 = __int_as_float(e1[k].y);
            a00 = fmaf(bflo(u0[k]), w0, a00); a01 = fmaf(bfhi(u0[k]), w0, a01);
            a10 = fmaf(bflo(u1[k]), w1, a10); a11 = fmaf(bfhi(u1[k]), w1, a11);
        }
    }

    // self-loop + bias + relu
    float d0 = dis[nd0], d1 = dis[nd1];
    unsigned us0 = Hu[(size_t)nd0 * 64 + lane];
    unsigned us1 = Hu[(size_t)nd1 * 64 + lane];
    float2 bb = ((const float2*)bias)[lane];
    a00 = fmaf(bflo(us0), d0 * d0, a00) + bb.x;
    a01 = fmaf(bfhi(us0), d0 * d0, a01) + bb.y;
    a10 = fmaf(bflo(us1), d1 * d1, a10) + bb.x;
    a11 = fmaf(bfhi(us1), d1 * d1, a11) + bb.y;
    a00 = a00 > 0.f ? a00 : 0.f;  a01 = a01 > 0.f ? a01 : 0.f;
    a10 = a10 > 0.f ? a10 : 0.f;  a11 = a11 > 0.f ? a11 : 0.f;

    if (!FUSE) {
        if (node0 < n) {
            unsigned pk = ((unsigned)f2bf(a01) << 16) | (unsigned)f2bf(a00);
            ((unsigned*)outb)[(size_t)node0 * 64 + lane] = pk;
        }
        if (node0 + 1 < n) {
            unsigned pk = ((unsigned)f2bf(a11) << 16) | (unsigned)f2bf(a10);
            ((unsigned*)outb)[(size_t)(node0 + 1) * 64 + lane] = pk;
        }
    } else {
        unsigned x0 = ((const unsigned*)x1b)[(size_t)nd0 * 64 + lane];
        unsigned x1v = ((const unsigned*)x1b)[(size_t)nd1 * 64 + lane];
        s[w * 2 + 0][2 * lane]     = a00 + bflo(x0);
        s[w * 2 + 0][2 * lane + 1] = a01 + bfhi(x0);
        s[w * 2 + 1][2 * lane]     = a10 + bflo(x1v);
        s[w * 2 + 1][2 * lane + 1] = a11 + bfhi(x1v);
        __syncthreads();
#pragma unroll
        for (int i = 0; i < 2; i++) {
            int node = node0 + i;
            bool act = (node < n) && (lane < 41);
            float val = 0.f;
            if (act) {
#pragma unroll 4
                for (int f = 0; f < 128; f++) val = fmaf(s[w * 2 + i][f], lw[f * 41 + lane], val);
                val += lb[lane];
            }
            float m = act ? val : -INFINITY;
#pragma unroll
            for (int off = 32; off > 0; off >>= 1) m = fmaxf(m, __shfl_xor(m, off, 64));
            float e = act ? expf(val - m) : 0.f;
#pragma unroll
            for (int off = 32; off > 0; off >>= 1) e += __shfl_xor(e, off, 64);
            if (act) out[(size_t)node * 41 + lane] = val - m - logf(e);
        }
    }
}

extern "C" void kernel_launch(void* const* d_in, const int* in_sizes, int n_in,
                              void* d_out, int out_size, void* d_ws, size_t ws_size,
                              hipStream_t stream) {
    const float* x  = (const float*)d_in[0];
    const int*   ei = (const int*)d_in[1];
    const float* W1 = (const float*)d_in[2];
    const float* b1 = (const float*)d_in[3];
    const float* W2 = (const float*)d_in[4];
    const float* b2 = (const float*)d_in[5];
    const float* lw = (const float*)d_in[6];
    const float* lb = (const float*)d_in[7];
    float* out = (float*)d_out;

    const int n = in_sizes[0] / 256;   // 100000
    const int E = in_sizes[1] / 2;     // 1600000
    const int* src = ei;
    const int* dst = ei + E;

    // workspace layout
    int*   cnt     = (int*)d_ws;                       // NPAD
    int*   offs    = cnt + NPAD;                       // NPAD
    int*   cursor  = offs + NPAD;                      // NPAD
    int*   partial = cursor + NPAD;                    // 1024
    float* dis     = (float*)(partial + 1024);         // NPAD
    size_t Epad    = ((size_t)E + 255) & ~(size_t)255;
    int2*  eadj    = (int2*)(dis + NPAD);              // Epad pairs (8 B)
    unsigned short* Wt1 = (unsigned short*)(eadj + Epad);  // 256*128 bf16
    unsigned short* Wt2 = Wt1 + 256 * 128;                 // 128*128 bf16
    unsigned short* Hb  = Wt2 + 128 * 128;                 // n*128 bf16
    unsigned short* X1b = Hb + (size_t)n * 128;            // n*128 bf16

    const int nscan = (n + CHUNK - 1) / CHUNK;

    hipMemsetAsync(cnt, 0, (size_t)n * sizeof(int), stream);
    wcast<<<(256 * 128 + 255) / 256, 256, 0, stream>>>(W1, Wt1, 256);
    wcast<<<(128 * 128 + 255) / 256, 256, 0, stream>>>(W2, Wt2, 128);

    // CSR build (reused by both layers)
    hist_kernel<<<(E + 255) / 256, 256, 0, stream>>>(dst, cnt, E);
    scan_partial<<<nscan, 256, 0, stream>>>(cnt, partial, n);
    scan_small<<<1, 64, 0, stream>>>(partial, nscan);
    scan_final<<<nscan, 256, 0, stream>>>(cnt, partial, offs, cursor, dis, n);
    {
        const int NBUCKET = 4;
        int W = (n + NBUCKET - 1) / NBUCKET;
        for (int p = 0; p < NBUCKET; p++) {
            int lo = p * W, hi = lo + W < n ? lo + W : n;
            permute_bucket<<<(E + 255) / 256, 256, 0, stream>>>(src, dst, dis, cursor, eadj, E, lo, hi);
        }
    }

    // layer 1: h = bf16(x @ W1); x1 = relu(agg) (bf16)
    gemm_mfma<false><<<(n + 63) / 64, 256, 0, stream>>>(x, Wt1, Hb, n, 256);
    gather_k<false><<<(n + 7) / 8, 256, 0, stream>>>(Hb, eadj, offs, cnt, dis, b1, X1b,
                                                     nullptr, nullptr, nullptr, nullptr, n);

    // layer 2 + fused JK head
    gemm_mfma<true><<<(n + 63) / 64, 256, 0, stream>>>(X1b, Wt2, Hb, n, 128);
    gather_k<true><<<(n + 7) / 8, 256, 0, stream>>>(Hb, eadj, offs, cnt, dis, b2, nullptr,
                                                    X1b, lw, lb, out, n);
}

// Round 5
// 625.970 us; speedup vs baseline: 1.1303x; 1.1303x over previous
//
#include <hip/hip_runtime.h>
#include <math.h>

// ---------------------------------------------------------------------------
// JKNet: 2-layer GCN (sym-norm A+I) + sum-JK + linear + log_softmax.
// Round 5: gather restructured — wave=1 node, lanes = 4 edge-groups x 16
// feature-lanes; each row read is one dwordx4 per lane (1 KB/instr in
// flight), tail via weight-zeroing (no branches). CSR/GEMM unchanged.
// ---------------------------------------------------------------------------

#define NPAD (1 << 17)   // padded node-array stride (N=100000)
#define CHUNK 1024       // scan chunk (elements per block)

typedef __attribute__((ext_vector_type(8))) short short8;
typedef __attribute__((ext_vector_type(4))) float f32x4;

__device__ inline unsigned short f2bf(float f) {
    unsigned u = __builtin_bit_cast(unsigned, f);
    return (unsigned short)((u + 0x7fffu + ((u >> 16) & 1u)) >> 16);
}
__device__ inline float bflo(unsigned u) { return __builtin_bit_cast(float, u << 16); }
__device__ inline float bfhi(unsigned u) { return __builtin_bit_cast(float, u & 0xffff0000u); }

// ---- CSR build ------------------------------------------------------------

__global__ void hist_kernel(const int* __restrict__ dst, int* __restrict__ cnt, int E) {
    int e = blockIdx.x * 256 + threadIdx.x;
    if (e < E) atomicAdd(&cnt[dst[e]], 1);
}

__global__ void scan_partial(const int* __restrict__ cnt, int* __restrict__ partial, int n) {
    __shared__ int sdata[4];
    int b = blockIdx.x, t = threadIdx.x;
    int base = b * CHUNK;
    int sum = 0;
    for (int i = t; i < CHUNK; i += 256) {
        int idx = base + i;
        if (idx < n) sum += cnt[idx];
    }
#pragma unroll
    for (int off = 32; off > 0; off >>= 1) sum += __shfl_down(sum, off, 64);
    if ((t & 63) == 0) sdata[t >> 6] = sum;
    __syncthreads();
    if (t == 0) partial[b] = sdata[0] + sdata[1] + sdata[2] + sdata[3];
}

__global__ void scan_small(int* partial, int nblk) {
    if (threadIdx.x == 0 && blockIdx.x == 0) {
        int acc = 0;
        for (int i = 0; i < nblk; i++) { int v = partial[i]; partial[i] = acc; acc += v; }
    }
}

__global__ void scan_final(const int* __restrict__ cnt, const int* __restrict__ partial,
                           int* __restrict__ offs, int* __restrict__ cursor,
                           float* __restrict__ dis, int n) {
    __shared__ int wsum[4];
    int b = blockIdx.x, t = threadIdx.x;
    int lane = t & 63, w = t >> 6;
    int base = b * CHUNK + t * 4;
    int v[4];
#pragma unroll
    for (int j = 0; j < 4; j++) v[j] = (base + j < n) ? cnt[base + j] : 0;
    int s4 = v[0] + v[1] + v[2] + v[3];
    int inc = s4;
#pragma unroll
    for (int off = 1; off < 64; off <<= 1) {
        int x = __shfl_up(inc, off, 64);
        if (lane >= off) inc += x;
    }
    if (lane == 63) wsum[w] = inc;
    __syncthreads();
    int woff = 0;
    for (int i = 0; i < 4; i++) if (i < w) woff += wsum[i];
    int pos = partial[b] + woff + (inc - s4);
#pragma unroll
    for (int j = 0; j < 4; j++) {
        int idx = base + j;
        if (idx < n) {
            offs[idx] = pos;
            cursor[idx] = pos;
            dis[idx] = rsqrtf((float)(v[j] + 1));  // deg = incoming + self-loop
            pos += v[j];
        }
    }
}

// Bucketed permute: edges with dst in [lo,hi) only — cursor atomics and eadj
// scatter writes stay inside an L2-resident window. Stores (src, dis[s]*dis[d]).
__global__ void permute_bucket(const int* __restrict__ src, const int* __restrict__ dst,
                               const float* __restrict__ dis,
                               int* __restrict__ cursor, int2* __restrict__ eadj,
                               int E, int lo, int hi) {
    int e = blockIdx.x * 256 + threadIdx.x;
    if (e < E) {
        int d = dst[e];
        if (d >= lo && d < hi) {
            int s = src[e];
            int pos = atomicAdd(&cursor[d], 1);
            float wt = dis[s] * dis[d];
            eadj[pos] = make_int2(s, __float_as_int(wt));
        }
    }
}

// ---- W cast+transpose: Wt[n][k] = bf16(W[k][n]) ---------------------------
__global__ void wcast(const float* __restrict__ W, unsigned short* __restrict__ Wt, int K) {
    int i = blockIdx.x * 256 + threadIdx.x;
    if (i < K * 128) {
        int k = i >> 7, nn = i & 127;
        Wt[nn * K + k] = f2bf(W[i]);
    }
}

// ---- MFMA GEMM: Hb[n,128](bf16) = A[n,K] @ W[K,128] -----------------------
template<bool ABF16>
__global__ __launch_bounds__(256) void gemm_mfma(const void* __restrict__ Ap,
                                                 const unsigned short* __restrict__ Wt,
                                                 unsigned short* __restrict__ Hb,
                                                 int n, int K) {
    __shared__ unsigned short bs[128 * 136];
    const int tid = threadIdx.x;
    const int wave = tid >> 6, lane = tid & 63;
    const int quad = lane >> 4, mrow = lane & 15;
    const int arow_g = blockIdx.x * 64 + wave * 16 + mrow;
    const int arow = arow_g < n ? arow_g : n - 1;

    f32x4 acc[8];
#pragma unroll
    for (int t = 0; t < 8; t++) acc[t] = (f32x4){0.f, 0.f, 0.f, 0.f};

    const float* Af = (const float*)Ap;
    const unsigned short* Ab = (const unsigned short*)Ap;

    for (int kc = 0; kc < K; kc += 128) {
        __syncthreads();
        for (int i = tid; i < 2048; i += 256) {
            int row = i >> 4, c8 = i & 15;
            *(short8*)&bs[row * 136 + c8 * 8] = *(const short8*)&Wt[row * K + kc + c8 * 8];
        }
        __syncthreads();
#pragma unroll
        for (int kt = 0; kt < 128; kt += 32) {
            union { short8 v; unsigned short u[8]; } A;
            if (ABF16) {
                A.v = *(const short8*)&Ab[(size_t)arow * K + kc + kt + quad * 8];
            } else {
                const float* ap = &Af[(size_t)arow * K + kc + kt + quad * 8];
                float4 p0 = *(const float4*)ap;
                float4 p1 = *(const float4*)(ap + 4);
                A.u[0] = f2bf(p0.x); A.u[1] = f2bf(p0.y);
                A.u[2] = f2bf(p0.z); A.u[3] = f2bf(p0.w);
                A.u[4] = f2bf(p1.x); A.u[5] = f2bf(p1.y);
                A.u[6] = f2bf(p1.z); A.u[7] = f2bf(p1.w);
            }
#pragma unroll
            for (int nt = 0; nt < 8; nt++) {
                short8 B = *(const short8*)&bs[(nt * 16 + mrow) * 136 + kt + quad * 8];
                acc[nt] = __builtin_amdgcn_mfma_f32_16x16x32_bf16(A.v, B, acc[nt], 0, 0, 0);
            }
        }
    }
    const int drow0 = blockIdx.x * 64 + wave * 16 + quad * 4;
#pragma unroll
    for (int r = 0; r < 4; r++) {
        int dr = drow0 + r;
        if (dr < n) {
#pragma unroll
            for (int nt = 0; nt < 8; nt++)
                Hb[(size_t)dr * 128 + nt * 16 + mrow] = f2bf(acc[nt][r]);
        }
    }
}

// ---- CSR gather (+optional fused JK head) ---------------------------------
// Wave = 1 node. lane = grp*16 + fl: grp in [0,4) picks an edge, fl in [0,16)
// picks a 16 B (8-feature) slice of the 256 B H-row — one dwordx4 per lane,
// 1 KB in flight per load instruction, x2 unroll. Tail edges: index clamped,
// weight zeroed (no branch). Cross-grp shuffle reduce at the end.
template<bool FUSE>
__global__ __launch_bounds__(256) void gather_k(const unsigned short* __restrict__ Hb,
                                                const int2* __restrict__ eadj,
                                                const int* __restrict__ offs,
                                                const int* __restrict__ cnt,
                                                const float* __restrict__ dis,
                                                const float* __restrict__ bias,
                                                unsigned short* __restrict__ outb,
                                                const unsigned short* __restrict__ x1b,
                                                const float* __restrict__ lw,
                                                const float* __restrict__ lb,
                                                float* __restrict__ out, int n) {
    __shared__ float s[4][128];
    const int w = threadIdx.x >> 6, lane = threadIdx.x & 63;
    const int grp = lane >> 4, fl = lane & 15;
    const int node = blockIdx.x * 4 + w;
    const int nd = node < n ? node : n - 1;
    const int st = offs[nd], c = cnt[nd];

    float acc[8];
#pragma unroll
    for (int k = 0; k < 8; k++) acc[k] = 0.f;

    const int2* ep = eadj + st;
    for (int j = 0; j < c; j += 8) {
        int i0 = j + grp, i1 = j + 4 + grp;
        int2 e0 = ep[i0 < c ? i0 : c - 1];
        int2 e1 = ep[i1 < c ? i1 : c - 1];
        float w0 = i0 < c ? __int_as_float(e0.y) : 0.f;
        float w1 = i1 < c ? __int_as_float(e1.y) : 0.f;
        uint4 r0 = *(const uint4*)(Hb + (size_t)e0.x * 128 + fl * 8);
        uint4 r1 = *(const uint4*)(Hb + (size_t)e1.x * 128 + fl * 8);
        acc[0] = fmaf(bflo(r0.x), w0, acc[0]); acc[1] = fmaf(bfhi(r0.x), w0, acc[1]);
        acc[2] = fmaf(bflo(r0.y), w0, acc[2]); acc[3] = fmaf(bfhi(r0.y), w0, acc[3]);
        acc[4] = fmaf(bflo(r0.z), w0, acc[4]); acc[5] = fmaf(bfhi(r0.z), w0, acc[5]);
        acc[6] = fmaf(bflo(r0.w), w0, acc[6]); acc[7] = fmaf(bfhi(r0.w), w0, acc[7]);
        acc[0] = fmaf(bflo(r1.x), w1, acc[0]); acc[1] = fmaf(bfhi(r1.x), w1, acc[1]);
        acc[2] = fmaf(bflo(r1.y), w1, acc[2]); acc[3] = fmaf(bfhi(r1.y), w1, acc[3]);
        acc[4] = fmaf(bflo(r1.z), w1, acc[4]); acc[5] = fmaf(bfhi(r1.z), w1, acc[5]);
        acc[6] = fmaf(bflo(r1.w), w1, acc[6]); acc[7] = fmaf(bfhi(r1.w), w1, acc[7]);
    }
    // reduce across the 4 edge-groups (lanes fl, fl+16, fl+32, fl+48)
#pragma unroll
    for (int k = 0; k < 8; k++) {
        acc[k] += __shfl_xor(acc[k], 16, 64);
        acc[k] += __shfl_xor(acc[k], 32, 64);
    }
    // self-loop + bias + relu (8 contiguous features per fl-lane)
    float dd = dis[nd], sn = dd * dd;
    uint4 rs = *(const uint4*)(Hb + (size_t)nd * 128 + fl * 8);
    float4 bb0 = ((const float4*)bias)[fl * 2];
    float4 bb1 = ((const float4*)bias)[fl * 2 + 1];
    acc[0] = fmaf(bflo(rs.x), sn, acc[0]) + bb0.x;
    acc[1] = fmaf(bfhi(rs.x), sn, acc[1]) + bb0.y;
    acc[2] = fmaf(bflo(rs.y), sn, acc[2]) + bb0.z;
    acc[3] = fmaf(bfhi(rs.y), sn, acc[3]) + bb0.w;
    acc[4] = fmaf(bflo(rs.z), sn, acc[4]) + bb1.x;
    acc[5] = fmaf(bfhi(rs.z), sn, acc[5]) + bb1.y;
    acc[6] = fmaf(bflo(rs.w), sn, acc[6]) + bb1.z;
    acc[7] = fmaf(bfhi(rs.w), sn, acc[7]) + bb1.w;
#pragma unroll
    for (int k = 0; k < 8; k++) acc[k] = acc[k] > 0.f ? acc[k] : 0.f;

    if (!FUSE) {
        if (node < n && grp == 0) {
            uint4 pk;
            pk.x = ((unsigned)f2bf(acc[1]) << 16) | (unsigned)f2bf(acc[0]);
            pk.y = ((unsigned)f2bf(acc[3]) << 16) | (unsigned)f2bf(acc[2]);
            pk.z = ((unsigned)f2bf(acc[5]) << 16) | (unsigned)f2bf(acc[4]);
            pk.w = ((unsigned)f2bf(acc[7]) << 16) | (unsigned)f2bf(acc[6]);
            *(uint4*)(outb + (size_t)node * 128 + fl * 8) = pk;
        }
    } else {
        if (grp == 0) {
            uint4 xv = *(const uint4*)(x1b + (size_t)nd * 128 + fl * 8);
            s[w][fl * 8 + 0] = acc[0] + bflo(xv.x);
            s[w][fl * 8 + 1] = acc[1] + bfhi(xv.x);
            s[w][fl * 8 + 2] = acc[2] + bflo(xv.y);
            s[w][fl * 8 + 3] = acc[3] + bfhi(xv.y);
            s[w][fl * 8 + 4] = acc[4] + bflo(xv.z);
            s[w][fl * 8 + 5] = acc[5] + bfhi(xv.z);
            s[w][fl * 8 + 6] = acc[6] + bflo(xv.w);
            s[w][fl * 8 + 7] = acc[7] + bfhi(xv.w);
        }
        __syncthreads();
        bool act = (node < n) && (lane < 41);
        float val = 0.f;
        if (act) {
#pragma unroll 4
            for (int f = 0; f < 128; f++) val = fmaf(s[w][f], lw[f * 41 + lane], val);
            val += lb[lane];
        }
        float m = act ? val : -INFINITY;
#pragma unroll
        for (int off = 32; off > 0; off >>= 1) m = fmaxf(m, __shfl_xor(m, off, 64));
        float e = act ? expf(val - m) : 0.f;
#pragma unroll
        for (int off = 32; off > 0; off >>= 1) e += __shfl_xor(e, off, 64);
        if (act) out[(size_t)node * 41 + lane] = val - m - logf(e);
    }
}

extern "C" void kernel_launch(void* const* d_in, const int* in_sizes, int n_in,
                              void* d_out, int out_size, void* d_ws, size_t ws_size,
                              hipStream_t stream) {
    const float* x  = (const float*)d_in[0];
    const int*   ei = (const int*)d_in[1];
    const float* W1 = (const float*)d_in[2];
    const float* b1 = (const float*)d_in[3];
    const float* W2 = (const float*)d_in[4];
    const float* b2 = (const float*)d_in[5];
    const float* lw = (const float*)d_in[6];
    const float* lb = (const float*)d_in[7];
    float* out = (float*)d_out;

    const int n = in_sizes[0] / 256;   // 100000
    const int E = in_sizes[1] / 2;     // 1600000
    const int* src = ei;
    const int* dst = ei + E;

    // workspace layout
    int*   cnt     = (int*)d_ws;                       // NPAD
    int*   offs    = cnt + NPAD;                       // NPAD
    int*   cursor  = offs + NPAD;                      // NPAD
    int*   partial = cursor + NPAD;                    // 1024
    float* dis     = (float*)(partial + 1024);         // NPAD
    size_t Epad    = ((size_t)E + 255) & ~(size_t)255;
    int2*  eadj    = (int2*)(dis + NPAD);              // Epad pairs (8 B)
    unsigned short* Wt1 = (unsigned short*)(eadj + Epad);  // 256*128 bf16
    unsigned short* Wt2 = Wt1 + 256 * 128;                 // 128*128 bf16
    unsigned short* Hb  = Wt2 + 128 * 128;                 // n*128 bf16
    unsigned short* X1b = Hb + (size_t)n * 128;            // n*128 bf16

    const int nscan = (n + CHUNK - 1) / CHUNK;

    hipMemsetAsync(cnt, 0, (size_t)n * sizeof(int), stream);
    wcast<<<(256 * 128 + 255) / 256, 256, 0, stream>>>(W1, Wt1, 256);
    wcast<<<(128 * 128 + 255) / 256, 256, 0, stream>>>(W2, Wt2, 128);

    // CSR build (reused by both layers)
    hist_kernel<<<(E + 255) / 256, 256, 0, stream>>>(dst, cnt, E);
    scan_partial<<<nscan, 256, 0, stream>>>(cnt, partial, n);
    scan_small<<<1, 64, 0, stream>>>(partial, nscan);
    scan_final<<<nscan, 256, 0, stream>>>(cnt, partial, offs, cursor, dis, n);
    {
        const int NBUCKET = 4;
        int W = (n + NBUCKET - 1) / NBUCKET;
        for (int p = 0; p < NBUCKET; p++) {
            int lo = p * W, hi = lo + W < n ? lo + W : n;
            permute_bucket<<<(E + 255) / 256, 256, 0, stream>>>(src, dst, dis, cursor, eadj, E, lo, hi);
        }
    }

    // layer 1: h = bf16(x @ W1); x1 = relu(agg) (bf16)
    gemm_mfma<false><<<(n + 63) / 64, 256, 0, stream>>>(x, Wt1, Hb, n, 256);
    gather_k<false><<<(n + 3) / 4, 256, 0, stream>>>(Hb, eadj, offs, cnt, dis, b1, X1b,
                                                     nullptr, nullptr, nullptr, nullptr, n);

    // layer 2 + fused JK head
    gemm_mfma<true><<<(n + 63) / 64, 256, 0, stream>>>(X1b, Wt2, Hb, n, 128);
    gather_k<true><<<(n + 3) / 4, 256, 0, stream>>>(Hb, eadj, offs, cnt, dis, b2, nullptr,
                                                    X1b, lw, lb, out, n);
}

// Round 6
// 608.432 us; speedup vs baseline: 1.1628x; 1.0288x over previous
//
#include <hip/hip_runtime.h>
#include <math.h>

// ---------------------------------------------------------------------------
// JKNet: 2-layer GCN (sym-norm A+I) + sum-JK + linear + log_softmax.
// Round 6: gather de-latencied — one wave-load grabs <=64 edges' (src,weight),
// per-edge metadata comes from shuffles (no memory in the loop), and row-loads
// are software-pipelined depth-2 (prefetch next 8 edges' rows before consuming
// current). Permute buckets 4 -> 2. GEMM/CSR otherwise unchanged.
// ---------------------------------------------------------------------------

#define NPAD (1 << 17)   // padded node-array stride (N=100000)
#define CHUNK 1024       // scan chunk (elements per block)

typedef __attribute__((ext_vector_type(8))) short short8;
typedef __attribute__((ext_vector_type(4))) float f32x4;

__device__ inline unsigned short f2bf(float f) {
    unsigned u = __builtin_bit_cast(unsigned, f);
    return (unsigned short)((u + 0x7fffu + ((u >> 16) & 1u)) >> 16);
}
__device__ inline float bflo(unsigned u) { return __builtin_bit_cast(float, u << 16); }
__device__ inline float bfhi(unsigned u) { return __builtin_bit_cast(float, u & 0xffff0000u); }

// ---- CSR build ------------------------------------------------------------

__global__ void hist_kernel(const int* __restrict__ dst, int* __restrict__ cnt, int E) {
    int e = blockIdx.x * 256 + threadIdx.x;
    if (e < E) atomicAdd(&cnt[dst[e]], 1);
}

__global__ void scan_partial(const int* __restrict__ cnt, int* __restrict__ partial, int n) {
    __shared__ int sdata[4];
    int b = blockIdx.x, t = threadIdx.x;
    int base = b * CHUNK;
    int sum = 0;
    for (int i = t; i < CHUNK; i += 256) {
        int idx = base + i;
        if (idx < n) sum += cnt[idx];
    }
#pragma unroll
    for (int off = 32; off > 0; off >>= 1) sum += __shfl_down(sum, off, 64);
    if ((t & 63) == 0) sdata[t >> 6] = sum;
    __syncthreads();
    if (t == 0) partial[b] = sdata[0] + sdata[1] + sdata[2] + sdata[3];
}

__global__ void scan_small(int* partial, int nblk) {
    if (threadIdx.x == 0 && blockIdx.x == 0) {
        int acc = 0;
        for (int i = 0; i < nblk; i++) { int v = partial[i]; partial[i] = acc; acc += v; }
    }
}

__global__ void scan_final(const int* __restrict__ cnt, const int* __restrict__ partial,
                           int* __restrict__ offs, int* __restrict__ cursor,
                           float* __restrict__ dis, int n) {
    __shared__ int wsum[4];
    int b = blockIdx.x, t = threadIdx.x;
    int lane = t & 63, w = t >> 6;
    int base = b * CHUNK + t * 4;
    int v[4];
#pragma unroll
    for (int j = 0; j < 4; j++) v[j] = (base + j < n) ? cnt[base + j] : 0;
    int s4 = v[0] + v[1] + v[2] + v[3];
    int inc = s4;
#pragma unroll
    for (int off = 1; off < 64; off <<= 1) {
        int x = __shfl_up(inc, off, 64);
        if (lane >= off) inc += x;
    }
    if (lane == 63) wsum[w] = inc;
    __syncthreads();
    int woff = 0;
    for (int i = 0; i < 4; i++) if (i < w) woff += wsum[i];
    int pos = partial[b] + woff + (inc - s4);
#pragma unroll
    for (int j = 0; j < 4; j++) {
        int idx = base + j;
        if (idx < n) {
            offs[idx] = pos;
            cursor[idx] = pos;
            dis[idx] = rsqrtf((float)(v[j] + 1));  // deg = incoming + self-loop
            pos += v[j];
        }
    }
}

// Bucketed permute: edges with dst in [lo,hi) only. Stores (src, dis[s]*dis[d]).
__global__ void permute_bucket(const int* __restrict__ src, const int* __restrict__ dst,
                               const float* __restrict__ dis,
                               int* __restrict__ cursor, int2* __restrict__ eadj,
                               int E, int lo, int hi) {
    int e = blockIdx.x * 256 + threadIdx.x;
    if (e < E) {
        int d = dst[e];
        if (d >= lo && d < hi) {
            int s = src[e];
            int pos = atomicAdd(&cursor[d], 1);
            float wt = dis[s] * dis[d];
            eadj[pos] = make_int2(s, __float_as_int(wt));
        }
    }
}

// ---- W cast+transpose: Wt[n][k] = bf16(W[k][n]) ---------------------------
__global__ void wcast(const float* __restrict__ W, unsigned short* __restrict__ Wt, int K) {
    int i = blockIdx.x * 256 + threadIdx.x;
    if (i < K * 128) {
        int k = i >> 7, nn = i & 127;
        Wt[nn * K + k] = f2bf(W[i]);
    }
}

// ---- MFMA GEMM: Hb[n,128](bf16) = A[n,K] @ W[K,128] -----------------------
template<bool ABF16>
__global__ __launch_bounds__(256) void gemm_mfma(const void* __restrict__ Ap,
                                                 const unsigned short* __restrict__ Wt,
                                                 unsigned short* __restrict__ Hb,
                                                 int n, int K) {
    __shared__ unsigned short bs[128 * 136];
    const int tid = threadIdx.x;
    const int wave = tid >> 6, lane = tid & 63;
    const int quad = lane >> 4, mrow = lane & 15;
    const int arow_g = blockIdx.x * 64 + wave * 16 + mrow;
    const int arow = arow_g < n ? arow_g : n - 1;

    f32x4 acc[8];
#pragma unroll
    for (int t = 0; t < 8; t++) acc[t] = (f32x4){0.f, 0.f, 0.f, 0.f};

    const float* Af = (const float*)Ap;
    const unsigned short* Ab = (const unsigned short*)Ap;

    for (int kc = 0; kc < K; kc += 128) {
        __syncthreads();
        for (int i = tid; i < 2048; i += 256) {
            int row = i >> 4, c8 = i & 15;
            *(short8*)&bs[row * 136 + c8 * 8] = *(const short8*)&Wt[row * K + kc + c8 * 8];
        }
        __syncthreads();
#pragma unroll
        for (int kt = 0; kt < 128; kt += 32) {
            union { short8 v; unsigned short u[8]; } A;
            if (ABF16) {
                A.v = *(const short8*)&Ab[(size_t)arow * K + kc + kt + quad * 8];
            } else {
                const float* ap = &Af[(size_t)arow * K + kc + kt + quad * 8];
                float4 p0 = *(const float4*)ap;
                float4 p1 = *(const float4*)(ap + 4);
                A.u[0] = f2bf(p0.x); A.u[1] = f2bf(p0.y);
                A.u[2] = f2bf(p0.z); A.u[3] = f2bf(p0.w);
                A.u[4] = f2bf(p1.x); A.u[5] = f2bf(p1.y);
                A.u[6] = f2bf(p1.z); A.u[7] = f2bf(p1.w);
            }
#pragma unroll
            for (int nt = 0; nt < 8; nt++) {
                short8 B = *(const short8*)&bs[(nt * 16 + mrow) * 136 + kt + quad * 8];
                acc[nt] = __builtin_amdgcn_mfma_f32_16x16x32_bf16(A.v, B, acc[nt], 0, 0, 0);
            }
        }
    }
    const int drow0 = blockIdx.x * 64 + wave * 16 + quad * 4;
#pragma unroll
    for (int r = 0; r < 4; r++) {
        int dr = drow0 + r;
        if (dr < n) {
#pragma unroll
            for (int nt = 0; nt < 8; nt++)
                Hb[(size_t)dr * 128 + nt * 16 + mrow] = f2bf(acc[nt][r]);
        }
    }
}

// ---- CSR gather (+optional fused JK head) ---------------------------------
// Wave = 1 node. lane = grp*16 + fl. One wave-load of eadj covers <=64 edges;
// (src,weight) broadcast via shuffles. Row loads (dwordx4/lane, 4 rows/instr)
// software-pipelined depth-2: prefetch edges j+8 while consuming j.
template<bool FUSE>
__global__ __launch_bounds__(256) void gather_k(const unsigned short* __restrict__ Hb,
                                                const int2* __restrict__ eadj,
                                                const int* __restrict__ offs,
                                                const int* __restrict__ cnt,
                                                const float* __restrict__ dis,
                                                const float* __restrict__ bias,
                                                unsigned short* __restrict__ outb,
                                                const unsigned short* __restrict__ x1b,
                                                const float* __restrict__ lw,
                                                const float* __restrict__ lb,
                                                float* __restrict__ out, int n) {
    __shared__ float s[4][128];
    const int w = threadIdx.x >> 6, lane = threadIdx.x & 63;
    const int grp = lane >> 4, fl = lane & 15;
    const int node = blockIdx.x * 4 + w;
    const int nd = node < n ? node : n - 1;
    const int st = offs[nd], c = cnt[nd];
    const unsigned short* Hfl = Hb + fl * 8;

    float acc[8];
#pragma unroll
    for (int k = 0; k < 8; k++) acc[k] = 0.f;

    const int2* ep = eadj + st;
    for (int kk = 0; kk < c; kk += 64) {
        int li = kk + lane;
        int2 me = ep[li < c ? li : c - 1];             // c>0 guaranteed in loop
        float mw = li < c ? __int_as_float(me.y) : 0.f;
        int cend = (c - kk) < 64 ? (c - kk) : 64;

        // prologue: edges grp / 4+grp
        int   s0 = __shfl(me.x, grp, 64);
        float w0 = __shfl(mw,  grp, 64);
        int   s1 = __shfl(me.x, 4 + grp, 64);
        float w1 = __shfl(mw,  4 + grp, 64);
        uint4 r0 = *(const uint4*)(Hfl + (size_t)s0 * 128);
        uint4 r1 = *(const uint4*)(Hfl + (size_t)s1 * 128);

        for (int j = 0; j < cend; j += 8) {
            int jn = (j + 8 < cend) ? j + 8 : j;       // wave-uniform select
            int   sn0 = __shfl(me.x, jn + grp, 64);
            float wn0 = __shfl(mw,  jn + grp, 64);
            int   sn1 = __shfl(me.x, jn + 4 + grp, 64);
            float wn1 = __shfl(mw,  jn + 4 + grp, 64);
            uint4 rn0 = *(const uint4*)(Hfl + (size_t)sn0 * 128);  // issued before
            uint4 rn1 = *(const uint4*)(Hfl + (size_t)sn1 * 128);  // consuming r0/r1
            acc[0] = fmaf(bflo(r0.x), w0, acc[0]); acc[1] = fmaf(bfhi(r0.x), w0, acc[1]);
            acc[2] = fmaf(bflo(r0.y), w0, acc[2]); acc[3] = fmaf(bfhi(r0.y), w0, acc[3]);
            acc[4] = fmaf(bflo(r0.z), w0, acc[4]); acc[5] = fmaf(bfhi(r0.z), w0, acc[5]);
            acc[6] = fmaf(bflo(r0.w), w0, acc[6]); acc[7] = fmaf(bfhi(r0.w), w0, acc[7]);
            acc[0] = fmaf(bflo(r1.x), w1, acc[0]); acc[1] = fmaf(bfhi(r1.x), w1, acc[1]);
            acc[2] = fmaf(bflo(r1.y), w1, acc[2]); acc[3] = fmaf(bfhi(r1.y), w1, acc[3]);
            acc[4] = fmaf(bflo(r1.z), w1, acc[4]); acc[5] = fmaf(bfhi(r1.z), w1, acc[5]);
            acc[6] = fmaf(bflo(r1.w), w1, acc[6]); acc[7] = fmaf(bfhi(r1.w), w1, acc[7]);
            r0 = rn0; r1 = rn1; w0 = wn0; w1 = wn1;
        }
    }
    // reduce across the 4 edge-groups
#pragma unroll
    for (int k = 0; k < 8; k++) {
        acc[k] += __shfl_xor(acc[k], 16, 64);
        acc[k] += __shfl_xor(acc[k], 32, 64);
    }
    // self-loop + bias + relu (8 contiguous features per fl-lane)
    float dd = dis[nd], sn = dd * dd;
    uint4 rs = *(const uint4*)(Hfl + (size_t)nd * 128);
    float4 bb0 = ((const float4*)bias)[fl * 2];
    float4 bb1 = ((const float4*)bias)[fl * 2 + 1];
    acc[0] = fmaf(bflo(rs.x), sn, acc[0]) + bb0.x;
    acc[1] = fmaf(bfhi(rs.x), sn, acc[1]) + bb0.y;
    acc[2] = fmaf(bflo(rs.y), sn, acc[2]) + bb0.z;
    acc[3] = fmaf(bfhi(rs.y), sn, acc[3]) + bb0.w;
    acc[4] = fmaf(bflo(rs.z), sn, acc[4]) + bb1.x;
    acc[5] = fmaf(bfhi(rs.z), sn, acc[5]) + bb1.y;
    acc[6] = fmaf(bflo(rs.w), sn, acc[6]) + bb1.z;
    acc[7] = fmaf(bfhi(rs.w), sn, acc[7]) + bb1.w;
#pragma unroll
    for (int k = 0; k < 8; k++) acc[k] = acc[k] > 0.f ? acc[k] : 0.f;

    if (!FUSE) {
        if (node < n && grp == 0) {
            uint4 pk;
            pk.x = ((unsigned)f2bf(acc[1]) << 16) | (unsigned)f2bf(acc[0]);
            pk.y = ((unsigned)f2bf(acc[3]) << 16) | (unsigned)f2bf(acc[2]);
            pk.z = ((unsigned)f2bf(acc[5]) << 16) | (unsigned)f2bf(acc[4]);
            pk.w = ((unsigned)f2bf(acc[7]) << 16) | (unsigned)f2bf(acc[6]);
            *(uint4*)(outb + (size_t)node * 128 + fl * 8) = pk;
        }
    } else {
        if (grp == 0) {
            uint4 xv = *(const uint4*)(x1b + (size_t)nd * 128 + fl * 8);
            s[w][fl * 8 + 0] = acc[0] + bflo(xv.x);
            s[w][fl * 8 + 1] = acc[1] + bfhi(xv.x);
            s[w][fl * 8 + 2] = acc[2] + bflo(xv.y);
            s[w][fl * 8 + 3] = acc[3] + bfhi(xv.y);
            s[w][fl * 8 + 4] = acc[4] + bflo(xv.z);
            s[w][fl * 8 + 5] = acc[5] + bfhi(xv.z);
            s[w][fl * 8 + 6] = acc[6] + bflo(xv.w);
            s[w][fl * 8 + 7] = acc[7] + bfhi(xv.w);
        }
        __syncthreads();
        bool act = (node < n) && (lane < 41);
        float val = 0.f;
        if (act) {
#pragma unroll 4
            for (int f = 0; f < 128; f++) val = fmaf(s[w][f], lw[f * 41 + lane], val);
            val += lb[lane];
        }
        float m = act ? val : -INFINITY;
#pragma unroll
        for (int off = 32; off > 0; off >>= 1) m = fmaxf(m, __shfl_xor(m, off, 64));
        float e = act ? expf(val - m) : 0.f;
#pragma unroll
        for (int off = 32; off > 0; off >>= 1) e += __shfl_xor(e, off, 64);
        if (act) out[(size_t)node * 41 + lane] = val - m - logf(e);
    }
}

extern "C" void kernel_launch(void* const* d_in, const int* in_sizes, int n_in,
                              void* d_out, int out_size, void* d_ws, size_t ws_size,
                              hipStream_t stream) {
    const float* x  = (const float*)d_in[0];
    const int*   ei = (const int*)d_in[1];
    const float* W1 = (const float*)d_in[2];
    const float* b1 = (const float*)d_in[3];
    const float* W2 = (const float*)d_in[4];
    const float* b2 = (const float*)d_in[5];
    const float* lw = (const float*)d_in[6];
    const float* lb = (const float*)d_in[7];
    float* out = (float*)d_out;

    const int n = in_sizes[0] / 256;   // 100000
    const int E = in_sizes[1] / 2;     // 1600000
    const int* src = ei;
    const int* dst = ei + E;

    // workspace layout
    int*   cnt     = (int*)d_ws;                       // NPAD
    int*   offs    = cnt + NPAD;                       // NPAD
    int*   cursor  = offs + NPAD;                      // NPAD
    int*   partial = cursor + NPAD;                    // 1024
    float* dis     = (float*)(partial + 1024);         // NPAD
    size_t Epad    = ((size_t)E + 255) & ~(size_t)255;
    int2*  eadj    = (int2*)(dis + NPAD);              // Epad pairs (8 B)
    unsigned short* Wt1 = (unsigned short*)(eadj + Epad);  // 256*128 bf16
    unsigned short* Wt2 = Wt1 + 256 * 128;                 // 128*128 bf16
    unsigned short* Hb  = Wt2 + 128 * 128;                 // n*128 bf16
    unsigned short* X1b = Hb + (size_t)n * 128;            // n*128 bf16

    const int nscan = (n + CHUNK - 1) / CHUNK;

    hipMemsetAsync(cnt, 0, (size_t)n * sizeof(int), stream);
    wcast<<<(256 * 128 + 255) / 256, 256, 0, stream>>>(W1, Wt1, 256);
    wcast<<<(128 * 128 + 255) / 256, 256, 0, stream>>>(W2, Wt2, 128);

    // CSR build (reused by both layers)
    hist_kernel<<<(E + 255) / 256, 256, 0, stream>>>(dst, cnt, E);
    scan_partial<<<nscan, 256, 0, stream>>>(cnt, partial, n);
    scan_small<<<1, 64, 0, stream>>>(partial, nscan);
    scan_final<<<nscan, 256, 0, stream>>>(cnt, partial, offs, cursor, dis, n);
    {
        const int NBUCKET = 2;
        int W = (n + NBUCKET - 1) / NBUCKET;
        for (int p = 0; p < NBUCKET; p++) {
            int lo = p * W, hi = lo + W < n ? lo + W : n;
            permute_bucket<<<(E + 255) / 256, 256, 0, stream>>>(src, dst, dis, cursor, eadj, E, lo, hi);
        }
    }

    // layer 1: h = bf16(x @ W1); x1 = relu(agg) (bf16)
    gemm_mfma<false><<<(n + 63) / 64, 256, 0, stream>>>(x, Wt1, Hb, n, 256);
    gather_k<false><<<(n + 3) / 4, 256, 0, stream>>>(Hb, eadj, offs, cnt, dis, b1, X1b,
                                                     nullptr, nullptr, nullptr, nullptr, n);

    // layer 2 + fused JK head
    gemm_mfma<true><<<(n + 63) / 64, 256, 0, stream>>>(X1b, Wt2, Hb, n, 128);
    gather_k<true><<<(n + 3) / 4, 256, 0, stream>>>(Hb, eadj, offs, cnt, dis, b2, nullptr,
                                                    X1b, lw, lb, out, n);
}